// Round 1
// baseline (661.216 us; speedup 1.0000x reference)
//
#include <hip/hip_runtime.h>
#include <cmath>

#define NUM_LEVELS 16
#define TABLE_SIZE 524288
#define TMASK (TABLE_SIZE - 1)
#define HASH_PRIME 2654435761u
#define T_SAMPLES 192
#define BLOCK 256

typedef __bf16 bf16x8 __attribute__((ext_vector_type(8)));
typedef float f32x4 __attribute__((ext_vector_type(4)));

struct LvlParams {
    float s[NUM_LEVELS];
    int   res[NUM_LEVELS];
    int   hashed[NUM_LEVELS];
};

__device__ __forceinline__ float softplus10(float x) {
    float t = 10.0f * x;
    float e = __expf(-fabsf(t));
    return (fmaxf(t, 0.0f) + __logf(1.0f + e)) * 0.1f;
}

__launch_bounds__(BLOCK, 3)
__global__ void nerf_fused(const float* __restrict__ x,
                           const float* __restrict__ emb,
                           const float* __restrict__ W0,
                           const float* __restrict__ b0,
                           const float* __restrict__ W1,
                           const float* __restrict__ b1,
                           float* __restrict__ out,
                           LvlParams lp) {
    // feats tile: 256 points x 64 features (bf16), padded to 72 (stride 144B
    // -> 4-bank row stride, 2-way max aliasing on b128 frag reads = free)
    __shared__ __bf16 feS[BLOCK][72];
    __shared__ __bf16 w0tS[64][72];   // W0 transposed: w0tS[n][k]
    __shared__ float  b0S[64];
    __shared__ float  w1S[64];

    const int tid = threadIdx.x;

    // ---- stage weights (once per block, barrier below covers it) ----
    #pragma unroll
    for (int i = 0; i < 16; ++i) {
        int e = i * 256 + tid;            // coalesced read of W0[4096]
        int k = e >> 6, n = e & 63;
        w0tS[n][k] = (__bf16)W0[e];
    }
    if (tid < 64) { b0S[tid] = b0[tid]; w1S[tid] = W1[tid]; }

    // ---- phase 1: ray setup + multires hash encode ----
    const int gp  = blockIdx.x * BLOCK + tid;
    const int ray = gp / T_SAMPLES;
    const int t   = gp - ray * T_SAMPLES;

    const float2 o  = *(const float2*)(x + (size_t)ray * (T_SAMPLES * 2));
    const float2 ep = *(const float2*)(x + (size_t)ray * (T_SAMPLES * 2) + (T_SAMPLES - 1) * 2);
    float rdx = ep.x - o.x, rdy = ep.y - o.y;
    float inv = 1.0f / sqrtf(rdx * rdx + rdy * rdy);
    rdx *= inv; rdy *= inv;
    const float z = (float)((double)t * (2.0 / 191.0));
    float px = fminf(fmaxf(o.x + rdx * z, -1.0f), 1.0f);
    float py = fminf(fmaxf(o.y + rdy * z, -1.0f), 1.0f);
    const float ux = (px + 1.0f) * 0.5f;
    const float uy = (py + 1.0f) * 0.5f;

    bf16x8 stage[8];
    #pragma unroll
    for (int l = 0; l < NUM_LEVELS; ++l) {
        const float s = lp.s[l];
        float posx = ux * s + 0.5f, posy = uy * s + 0.5f;
        float pfx = floorf(posx), pfy = floorf(posy);
        float fx = posx - pfx, fy = posy - pfy;
        int cx = (int)pfx, cy = (int)pfy;
        const f32x4* tb = (const f32x4*)(emb + (size_t)l * (TABLE_SIZE * 4));
        int i00, i01, i10, i11;
        if (lp.hashed[l]) {
            unsigned hy0 = (unsigned)cy * HASH_PRIME;
            unsigned hy1 = (unsigned)(cy + 1) * HASH_PRIME;
            i00 = (int)(((unsigned)cx ^ hy0) & TMASK);
            i01 = (int)(((unsigned)cx ^ hy1) & TMASK);
            i10 = (int)(((unsigned)(cx + 1) ^ hy0) & TMASK);
            i11 = (int)(((unsigned)(cx + 1) ^ hy1) & TMASK);
        } else {
            int res = lp.res[l];
            i00 = cy * res + cx; i10 = i00 + 1;
            i01 = i00 + res;     i11 = i01 + 1;
        }
        f32x4 c00 = tb[i00], c01 = tb[i01], c10 = tb[i10], c11 = tb[i11];
        float w00 = (1.0f - fx) * (1.0f - fy), w01 = (1.0f - fx) * fy;
        float w10 = fx * (1.0f - fy),          w11 = fx * fy;
        f32x4 a = c00 * w00 + c01 * w01 + c10 * w10 + c11 * w11;
        const int sj = l >> 1, so = (l & 1) * 4;
        stage[sj][so + 0] = (__bf16)a.x;
        stage[sj][so + 1] = (__bf16)a.y;
        stage[sj][so + 2] = (__bf16)a.z;
        stage[sj][so + 3] = (__bf16)a.w;
    }
    {
        bf16x8* frow = (bf16x8*)&feS[tid][0];   // row start 144B-aligned? 144=9*16 -> yes
        #pragma unroll
        for (int j = 0; j < 8; ++j) frow[j] = stage[j];
    }

    __syncthreads();

    // ---- phase 2: per-wave [64x64] @ [64x64] MFMA ----
    const int lane = tid & 63, wave = tid >> 6;
    const int lx = lane & 15, q = lane >> 4;

    f32x4 acc[4][4];
    #pragma unroll
    for (int mt = 0; mt < 4; ++mt)
        #pragma unroll
        for (int nt = 0; nt < 4; ++nt)
            acc[mt][nt] = (f32x4)(0.0f);

    #pragma unroll
    for (int kc = 0; kc < 2; ++kc) {
        const int koff = kc * 32 + q * 8;
        bf16x8 afr[4], bfr[4];
        #pragma unroll
        for (int mt = 0; mt < 4; ++mt)
            afr[mt] = *(const bf16x8*)&feS[wave * 64 + mt * 16 + lx][koff];
        #pragma unroll
        for (int nt = 0; nt < 4; ++nt)
            bfr[nt] = *(const bf16x8*)&w0tS[nt * 16 + lx][koff];
        #pragma unroll
        for (int mt = 0; mt < 4; ++mt)
            #pragma unroll
            for (int nt = 0; nt < 4; ++nt)
                acc[mt][nt] = __builtin_amdgcn_mfma_f32_16x16x32_bf16(
                    afr[mt], bfr[nt], acc[mt][nt], 0, 0, 0);
    }

    // ---- epilogue: softplus10 -> dot W1 -> reduce over 16 col-lanes ----
    float b0v[4], w1v[4];
    #pragma unroll
    for (int nt = 0; nt < 4; ++nt) {
        b0v[nt] = b0S[nt * 16 + lx];
        w1v[nt] = w1S[nt * 16 + lx];
    }
    const float b1v = b1[0];
    const float d0 = (float)(1.0 / 192.0);
    const float d1 = (float)(2.0 / 191.0);

    #pragma unroll
    for (int mt = 0; mt < 4; ++mt) {
        float part[4];
        #pragma unroll
        for (int r = 0; r < 4; ++r) {
            float p = 0.0f;
            #pragma unroll
            for (int nt = 0; nt < 4; ++nt)
                p += softplus10(acc[mt][nt][r] + b0v[nt]) * w1v[nt];
            p += __shfl_xor(p, 1, 64);
            p += __shfl_xor(p, 2, 64);
            p += __shfl_xor(p, 4, 64);
            p += __shfl_xor(p, 8, 64);
            part[r] = p;
        }
        if (lx == 0) {
            const int g0 = blockIdx.x * BLOCK + wave * 64 + mt * 16 + q * 4;
            const int tt = g0 % T_SAMPLES;           // multiple of 4, no wrap in vec4
            f32x4 ov;
            ov.x = softplus10(part[0] + b1v) * (tt == 0 ? d0 : d1);
            ov.y = softplus10(part[1] + b1v) * d1;
            ov.z = softplus10(part[2] + b1v) * d1;
            ov.w = softplus10(part[3] + b1v) * d1;
            *(f32x4*)(out + g0) = ov;
        }
    }
}

extern "C" void kernel_launch(void* const* d_in, const int* in_sizes, int n_in,
                              void* d_out, int out_size, void* d_ws, size_t ws_size,
                              hipStream_t stream) {
    const float* x   = (const float*)d_in[0];
    const float* emb = (const float*)d_in[1];
    const float* W0  = (const float*)d_in[2];
    const float* b0  = (const float*)d_in[3];
    const float* W1  = (const float*)d_in[4];
    const float* b1  = (const float*)d_in[5];
    float* out = (float*)d_out;

    // Replicate numpy's level constants with the same double-precision libm ops.
    LvlParams lp;
    const double bb = std::exp((std::log(2048.0) - std::log(2.0)) / 15.0);
    for (int l = 0; l < NUM_LEVELS; ++l) {
        double sc = 2.0 * std::pow(bb, (double)l) - 1.0;
        int rr = (int)std::ceil(sc) + 1;
        lp.s[l] = (float)sc;
        lp.res[l] = rr;
        lp.hashed[l] = ((long long)rr * (long long)rr > (long long)TABLE_SIZE) ? 1 : 0;
    }

    const int nblk = (out_size + BLOCK - 1) / BLOCK;   // 1572864/256 = 6144
    nerf_fused<<<nblk, BLOCK, 0, stream>>>(x, emb, W0, b0, W1, b1, out, lp);
}

// Round 2
// 592.430 us; speedup vs baseline: 1.1161x; 1.1161x over previous
//
#include <hip/hip_runtime.h>
#include <cmath>

#define NUM_LEVELS 16
#define TABLE_SIZE 524288
#define TMASK (TABLE_SIZE - 1)
#define HASH_PRIME 2654435761u
#define T_SAMPLES 192
#define BLOCK 256

typedef __bf16 bf16x8 __attribute__((ext_vector_type(8)));
typedef float f32x4 __attribute__((ext_vector_type(4)));

struct LvlParams {
    float s[NUM_LEVELS];
    int   res[NUM_LEVELS];
    int   hashed[NUM_LEVELS];
};

__device__ __forceinline__ float softplus10(float x) {
    float t = 10.0f * x;
    float e = __expf(-fabsf(t));
    return (fmaxf(t, 0.0f) + __logf(1.0f + e)) * 0.1f;
}

typedef __attribute__((address_space(1))) const void CGV;
typedef __attribute__((address_space(3))) void LDSV;

__device__ __forceinline__ void dma_gather16(const void* gaddr, void* lds_wave_base) {
    // per-lane global address; LDS dest = wave-uniform base + lane*16 (m104 semantics)
    __builtin_amdgcn_global_load_lds((CGV*)gaddr, (LDSV*)lds_wave_base, 16, 0, 0);
}

__device__ __forceinline__ void corner_idx(int cx, int cy, int res, int hashed,
                                           int& i00, int& i01, int& i10, int& i11) {
    if (hashed) {
        unsigned hy0 = (unsigned)cy * HASH_PRIME;
        unsigned hy1 = (unsigned)(cy + 1) * HASH_PRIME;
        i00 = (int)(((unsigned)cx ^ hy0) & TMASK);
        i01 = (int)(((unsigned)cx ^ hy1) & TMASK);
        i10 = (int)(((unsigned)(cx + 1) ^ hy0) & TMASK);
        i11 = (int)(((unsigned)(cx + 1) ^ hy1) & TMASK);
    } else {
        i00 = cy * res + cx; i10 = i00 + 1;
        i01 = i00 + res;     i11 = i01 + 1;
    }
}

__launch_bounds__(BLOCK, 3)
__global__ void nerf_fused(const float* __restrict__ x,
                           const float* __restrict__ emb,
                           const float* __restrict__ W0,
                           const float* __restrict__ b0,
                           const float* __restrict__ W1,
                           const float* __restrict__ b1,
                           float* __restrict__ out,
                           LvlParams lp) {
    // Union region: first used as DMA landing zone for levels 14,15
    // (2 lvl x 4 corners x 4 waves x 64 lanes x 16B = 32 KB), then (after a
    // barrier) as the bf16 feats tile [256][72] (36.9 KB). Total LDS 46.6 KB
    // -> 3 blocks/CU, same as round 1.
    __shared__ __align__(16) char uSh[BLOCK * 72 * 2];
    __shared__ __bf16 w0tS[64][72];   // W0 transposed: w0tS[n][k]
    __shared__ float  b0S[64];
    __shared__ float  w1S[64];

    const int tid  = threadIdx.x;
    const int lane = tid & 63, wave = tid >> 6;

    // ---- stage weights (VMEM issued before all gathers; oldest in vmcnt) ----
    #pragma unroll
    for (int i = 0; i < 16; ++i) {
        int e = i * 256 + tid;            // coalesced read of W0[4096]
        int k = e >> 6, n = e & 63;
        w0tS[n][k] = (__bf16)W0[e];
    }
    if (tid < 64) { b0S[tid] = b0[tid]; w1S[tid] = W1[tid]; }

    // ---- ray setup ----
    const int gp  = blockIdx.x * BLOCK + tid;
    const int ray = gp / T_SAMPLES;
    const int t   = gp - ray * T_SAMPLES;

    const float2 o  = *(const float2*)(x + (size_t)ray * (T_SAMPLES * 2));
    const float2 ep = *(const float2*)(x + (size_t)ray * (T_SAMPLES * 2) + (T_SAMPLES - 1) * 2);
    float rdx = ep.x - o.x, rdy = ep.y - o.y;
    float inv = 1.0f / sqrtf(rdx * rdx + rdy * rdy);
    rdx *= inv; rdy *= inv;
    const float z = (float)((double)t * (2.0 / 191.0));
    float px = fminf(fmaxf(o.x + rdx * z, -1.0f), 1.0f);
    float py = fminf(fmaxf(o.y + rdy * z, -1.0f), 1.0f);
    const float ux = (px + 1.0f) * 0.5f;
    const float uy = (py + 1.0f) * 0.5f;

    f32x4* land = (f32x4*)uSh;   // slot = ((lvl*4+c)*4 + wave)*64 + lane

    // ---- issue DMA gathers for levels 14,15 (no VGPR held, in flight now) --
    float frx[2], fry[2];        // fractional coords for levels 14,15
    #pragma unroll
    for (int li = 0; li < 2; ++li) {
        const int l = 14 + li;
        float posx = ux * lp.s[l] + 0.5f, posy = uy * lp.s[l] + 0.5f;
        float pfx = floorf(posx), pfy = floorf(posy);
        frx[li] = posx - pfx; fry[li] = posy - pfy;
        int cx = (int)pfx, cy = (int)pfy;
        int i00, i01, i10, i11;
        corner_idx(cx, cy, lp.res[l], lp.hashed[l], i00, i01, i10, i11);
        const f32x4* tb = (const f32x4*)(emb + (size_t)l * (TABLE_SIZE * 4));
        dma_gather16(tb + i00, land + ((li * 4 + 0) * 4 + wave) * 64);
        dma_gather16(tb + i01, land + ((li * 4 + 1) * 4 + wave) * 64);
        dma_gather16(tb + i10, land + ((li * 4 + 2) * 4 + wave) * 64);
        dma_gather16(tb + i11, land + ((li * 4 + 3) * 4 + wave) * 64);
    }

    // ---- issue register loads for levels 12,13 (held across 0-11) ----
    f32x4 cre[8]; float frx2[2], fry2[2];
    #pragma unroll
    for (int li = 0; li < 2; ++li) {
        const int l = 12 + li;
        float posx = ux * lp.s[l] + 0.5f, posy = uy * lp.s[l] + 0.5f;
        float pfx = floorf(posx), pfy = floorf(posy);
        frx2[li] = posx - pfx; fry2[li] = posy - pfy;
        int cx = (int)pfx, cy = (int)pfy;
        int i00, i01, i10, i11;
        corner_idx(cx, cy, lp.res[l], lp.hashed[l], i00, i01, i10, i11);
        const f32x4* tb = (const f32x4*)(emb + (size_t)l * (TABLE_SIZE * 4));
        cre[li * 4 + 0] = tb[i00];
        cre[li * 4 + 1] = tb[i01];
        cre[li * 4 + 2] = tb[i10];
        cre[li * 4 + 3] = tb[i11];
    }

    // ---- levels 0..11: small tables, L1/L2-hot, computed while DMAs fly ----
    bf16x8 stage[8];
    #pragma unroll
    for (int l = 0; l < 12; ++l) {
        float posx = ux * lp.s[l] + 0.5f, posy = uy * lp.s[l] + 0.5f;
        float pfx = floorf(posx), pfy = floorf(posy);
        float fx = posx - pfx, fy = posy - pfy;
        int cx = (int)pfx, cy = (int)pfy;
        int i00, i01, i10, i11;
        corner_idx(cx, cy, lp.res[l], lp.hashed[l], i00, i01, i10, i11);
        const f32x4* tb = (const f32x4*)(emb + (size_t)l * (TABLE_SIZE * 4));
        f32x4 c00 = tb[i00], c01 = tb[i01], c10 = tb[i10], c11 = tb[i11];
        float w00 = (1.0f - fx) * (1.0f - fy), w01 = (1.0f - fx) * fy;
        float w10 = fx * (1.0f - fy),          w11 = fx * fy;
        f32x4 a = c00 * w00 + c01 * w01 + c10 * w10 + c11 * w11;
        const int sj = l >> 1, so = (l & 1) * 4;
        stage[sj][so + 0] = (__bf16)a.x;
        stage[sj][so + 1] = (__bf16)a.y;
        stage[sj][so + 2] = (__bf16)a.z;
        stage[sj][so + 3] = (__bf16)a.w;
    }

    // ---- consume levels 12,13 from registers ----
    #pragma unroll
    for (int li = 0; li < 2; ++li) {
        const int l = 12 + li;
        float fx = frx2[li], fy = fry2[li];
        float w00 = (1.0f - fx) * (1.0f - fy), w01 = (1.0f - fx) * fy;
        float w10 = fx * (1.0f - fy),          w11 = fx * fy;
        f32x4 a = cre[li * 4 + 0] * w00 + cre[li * 4 + 1] * w01
                + cre[li * 4 + 2] * w10 + cre[li * 4 + 3] * w11;
        const int sj = l >> 1, so = (l & 1) * 4;
        stage[sj][so + 0] = (__bf16)a.x;
        stage[sj][so + 1] = (__bf16)a.y;
        stage[sj][so + 2] = (__bf16)a.z;
        stage[sj][so + 3] = (__bf16)a.w;
    }

    // ---- consume levels 14,15 from the LDS landing zone ----
    __builtin_amdgcn_s_waitcnt(0x0F70);   // vmcnt(0): DMA LDS writes visible
    #pragma unroll
    for (int li = 0; li < 2; ++li) {
        const int l = 14 + li;
        f32x4 c00 = land[((li * 4 + 0) * 4 + wave) * 64 + lane];
        f32x4 c01 = land[((li * 4 + 1) * 4 + wave) * 64 + lane];
        f32x4 c10 = land[((li * 4 + 2) * 4 + wave) * 64 + lane];
        f32x4 c11 = land[((li * 4 + 3) * 4 + wave) * 64 + lane];
        float fx = frx[li], fy = fry[li];
        float w00 = (1.0f - fx) * (1.0f - fy), w01 = (1.0f - fx) * fy;
        float w10 = fx * (1.0f - fy),          w11 = fx * fy;
        f32x4 a = c00 * w00 + c01 * w01 + c10 * w10 + c11 * w11;
        const int sj = l >> 1, so = (l & 1) * 4;
        stage[sj][so + 0] = (__bf16)a.x;
        stage[sj][so + 1] = (__bf16)a.y;
        stage[sj][so + 2] = (__bf16)a.z;
        stage[sj][so + 3] = (__bf16)a.w;
    }

    __syncthreads();   // everyone done reading the landing zone (aliases feS)

    __bf16 (*feS)[72] = (__bf16 (*)[72])uSh;
    {
        bf16x8* frow = (bf16x8*)&feS[tid][0];   // 144B row stride, 16B aligned
        #pragma unroll
        for (int j = 0; j < 8; ++j) frow[j] = stage[j];
    }

    __syncthreads();

    // ---- phase 2: per-wave [64x64] @ [64x64] MFMA ----
    const int lx = lane & 15, q = lane >> 4;

    f32x4 acc[4][4];
    #pragma unroll
    for (int mt = 0; mt < 4; ++mt)
        #pragma unroll
        for (int nt = 0; nt < 4; ++nt)
            acc[mt][nt] = (f32x4)(0.0f);

    #pragma unroll
    for (int kc = 0; kc < 2; ++kc) {
        const int koff = kc * 32 + q * 8;
        bf16x8 afr[4], bfr[4];
        #pragma unroll
        for (int mt = 0; mt < 4; ++mt)
            afr[mt] = *(const bf16x8*)&feS[wave * 64 + mt * 16 + lx][koff];
        #pragma unroll
        for (int nt = 0; nt < 4; ++nt)
            bfr[nt] = *(const bf16x8*)&w0tS[nt * 16 + lx][koff];
        #pragma unroll
        for (int mt = 0; mt < 4; ++mt)
            #pragma unroll
            for (int nt = 0; nt < 4; ++nt)
                acc[mt][nt] = __builtin_amdgcn_mfma_f32_16x16x32_bf16(
                    afr[mt], bfr[nt], acc[mt][nt], 0, 0, 0);
    }

    // ---- epilogue: softplus10 -> dot W1 -> reduce over 16 col-lanes ----
    float b0v[4], w1v[4];
    #pragma unroll
    for (int nt = 0; nt < 4; ++nt) {
        b0v[nt] = b0S[nt * 16 + lx];
        w1v[nt] = w1S[nt * 16 + lx];
    }
    const float b1v = b1[0];
    const float d0 = (float)(1.0 / 192.0);
    const float d1 = (float)(2.0 / 191.0);

    #pragma unroll
    for (int mt = 0; mt < 4; ++mt) {
        float part[4];
        #pragma unroll
        for (int r = 0; r < 4; ++r) {
            float p = 0.0f;
            #pragma unroll
            for (int nt = 0; nt < 4; ++nt)
                p += softplus10(acc[mt][nt][r] + b0v[nt]) * w1v[nt];
            p += __shfl_xor(p, 1, 64);
            p += __shfl_xor(p, 2, 64);
            p += __shfl_xor(p, 4, 64);
            p += __shfl_xor(p, 8, 64);
            part[r] = p;
        }
        if (lx == 0) {
            const int g0 = blockIdx.x * BLOCK + wave * 64 + mt * 16 + q * 4;
            const int tt = g0 % T_SAMPLES;           // multiple of 4, no wrap in vec4
            f32x4 ov;
            ov.x = softplus10(part[0] + b1v) * (tt == 0 ? d0 : d1);
            ov.y = softplus10(part[1] + b1v) * d1;
            ov.z = softplus10(part[2] + b1v) * d1;
            ov.w = softplus10(part[3] + b1v) * d1;
            *(f32x4*)(out + g0) = ov;
        }
    }
}

extern "C" void kernel_launch(void* const* d_in, const int* in_sizes, int n_in,
                              void* d_out, int out_size, void* d_ws, size_t ws_size,
                              hipStream_t stream) {
    const float* x   = (const float*)d_in[0];
    const float* emb = (const float*)d_in[1];
    const float* W0  = (const float*)d_in[2];
    const float* b0  = (const float*)d_in[3];
    const float* W1  = (const float*)d_in[4];
    const float* b1  = (const float*)d_in[5];
    float* out = (float*)d_out;

    // Replicate numpy's level constants with the same double-precision libm ops.
    LvlParams lp;
    const double bb = std::exp((std::log(2048.0) - std::log(2.0)) / 15.0);
    for (int l = 0; l < NUM_LEVELS; ++l) {
        double sc = 2.0 * std::pow(bb, (double)l) - 1.0;
        int rr = (int)std::ceil(sc) + 1;
        lp.s[l] = (float)sc;
        lp.res[l] = rr;
        lp.hashed[l] = ((long long)rr * (long long)rr > (long long)TABLE_SIZE) ? 1 : 0;
    }

    const int nblk = (out_size + BLOCK - 1) / BLOCK;   // 1572864/256 = 6144
    nerf_fused<<<nblk, BLOCK, 0, stream>>>(x, emb, W0, b0, W1, b1, out, lp);
}